// Round 8
// baseline (709.182 us; speedup 1.0000x reference)
//
#include <hip/hip_runtime.h>

#define NN 1024
#define TT 256
#define MAXDEG 96

typedef unsigned short u16;

// LDS x layout (words, rank-indexed), per buffer xb[b][3104]:
//   [0..1023]    copy A: rank v at word v
//   [1024..2047] copy B: word 1024 + ((v&~31) | ((v&31)^h)),          h=(v>>5)&31
//   [2048..3071] copy C: word 2048 + ((v&~31) | ((v&31)^((13h+5)&31)))
//   [3072..3103] zero sentinels (one per bank)

__device__ __forceinline__ int bofsB(int v) {
    int h = (v >> 5) & 31;
    return 1024 + ((v & ~31) | ((v & 31) ^ h));
}
__device__ __forceinline__ int bofsC(int v) {
    int h = (v >> 5) & 31;
    return 2048 + ((v & ~31) | ((v & 31) ^ ((13 * h + 5) & 31)));
}

// ---- K1: per-chunk nonzero counts of each adj column (coalesced) ----
__global__ __launch_bounds__(64) void k1_count(const float* __restrict__ adj,
                                               int* __restrict__ cnt_part)
{
    int tid = blockIdx.x * 64 + threadIdx.x;
    int chunk = tid >> 10;
    int n = tid & 1023;
    int c = 0;
    for (int j = 0; j < 64; ++j)
        c += (adj[(chunk * 64 + j) * NN + n] != 0.0f) ? 1 : 0;
    cnt_part[chunk * NN + n] = c;
}

// ---- K2: totals -> deg, pdeg (slack +8..15 for the bank matcher) ----
__global__ __launch_bounds__(256) void k2_totals(const int* __restrict__ cnt_part,
                                                 int* __restrict__ deg,
                                                 int* __restrict__ pdeg)
{
    int n = blockIdx.x * 256 + threadIdx.x;
    int tot = 0;
    for (int c = 0; c < 16; ++c) tot += cnt_part[c * NN + n];
    deg[n] = tot;
    int cap = tot < MAXDEG ? tot : MAXDEG;
    int pd = (cap + 15) & ~7;
    if (pd < 16) pd = 16;
    if (pd > MAXDEG) pd = MAXDEG;
    pdeg[n] = pd;
}

// ---- K3: stable descending-pdeg rank ----
__global__ __launch_bounds__(256) void k3_rank(const int* __restrict__ pdeg,
                                               int* __restrict__ rank_of,
                                               int* __restrict__ node_of)
{
    int n = blockIdx.x * 256 + threadIdx.x;
    int my = pdeg[n];
    int r = 0;
    for (int m = 0; m < NN; ++m) {
        int pm = pdeg[m];
        r += (pm > my) || (pm == my && m < n);
    }
    rank_of[n] = r;
    node_of[r] = n;
}

// ---- K4: fill compact neighbor lists (coalesced column scan) ----
__global__ __launch_bounds__(64) void k4_fill(const float* __restrict__ adj,
                                              const int* __restrict__ cnt_part,
                                              u16* __restrict__ nbrC)
{
    int tid = blockIdx.x * 64 + threadIdx.x;
    int chunk = tid >> 10;
    int n = tid & 1023;
    int pos = 0;
    for (int c = 0; c < chunk; ++c) pos += cnt_part[c * NN + n];
    for (int j = 0; j < 64; ++j) {
        int m = chunk * 64 + j;
        if (adj[m * NN + n] != 0.0f) {
            if (pos < MAXDEG) nbrC[n * MAXDEG + pos] = (u16)m;
            ++pos;
        }
    }
}

// ---- K5: three-choice + depth-1-eviction bank schedule (cuckoo-style) ----
// LDS arrays are lane-major int: who[k][tl] -> bank = tl&31 (2 lanes/bank, free).
__global__ __launch_bounds__(64) void k5_sched(const u16* __restrict__ nbrC,
                                               const int* __restrict__ deg,
                                               const int* __restrict__ pdeg,
                                               const int* __restrict__ rank_of,
                                               u16* __restrict__ nbr8,
                                               int* __restrict__ ngrp_r,
                                               float* __restrict__ invd_r)
{
    __shared__ int nrk[MAXDEG][64];   // neighbor ranks
    __shared__ int who[MAXDEG][64];   // slot -> neighbor rank, -1 = free
    const int tl = threadIdx.x;
    const int n  = blockIdx.x * 64 + tl;
    const int r  = rank_of[n];
    const int l  = r & 63;
    const int dg = deg[n];
    const int cap = dg < MAXDEG ? dg : MAXDEG;
    const int pd = pdeg[n];

    for (int j = 0; j < cap; ++j) nrk[j][tl] = rank_of[nbrC[n * MAXDEG + j]];
    for (int k = 0; k < pd; ++k) who[k][tl] = -1;

#define BANKS(V, B0, B1, B2)                                     \
    int B0 = (V) & 31;                                           \
    int h_ = ((V) >> 5) & 31;                                    \
    int B1 = B0 ^ h_;                                            \
    int B2 = B0 ^ ((13 * h_ + 5) & 31);

    unsigned int plmask[3] = {0u, 0u, 0u};

    // pass 1: three-choice first-fit
    for (int j = 0; j < cap; ++j) {
        int v = nrk[j][tl];
        BANKS(v, b0, b1, b2)
        int bs[3] = {b0, b1, b2};
        int placed = 0;
        for (int c = 0; c < 3 && !placed; ++c) {
            int res = (bs[c] - l) & 31;
            for (int k = res; k < pd; k += 32)
                if (who[k][tl] < 0) { who[k][tl] = v; placed = 1; break; }
        }
        if (placed) plmask[j >> 5] |= 1u << (j & 31);
    }
    // pass 2: depth-1 eviction
    for (int j = 0; j < cap; ++j) {
        if (plmask[j >> 5] & (1u << (j & 31))) continue;
        int v = nrk[j][tl];
        BANKS(v, b0, b1, b2)
        int bs[3] = {b0, b1, b2};
        int placed = 0;
        for (int c = 0; c < 3 && !placed; ++c) {
            int res = (bs[c] - l) & 31;
            for (int k = res; k < pd && !placed; k += 32) {
                int vo = who[k][tl];
                if (vo < 0) { who[k][tl] = v; placed = 1; break; }
                BANKS(vo, o0, o1, o2)
                int os[3] = {o0, o1, o2};
                for (int c2 = 0; c2 < 3 && !placed; ++c2) {
                    int res2 = (os[c2] - l) & 31;
                    for (int k2 = res2; k2 < pd; k2 += 32) {
                        if (k2 != k && who[k2][tl] < 0) {
                            who[k2][tl] = vo;
                            who[k][tl]  = v;
                            placed = 1; break;
                        }
                    }
                }
            }
        }
        if (placed) plmask[j >> 5] |= 1u << (j & 31);
    }
    // pass 3: overflow anywhere free
    for (int j = 0; j < cap; ++j) {
        if (plmask[j >> 5] & (1u << (j & 31))) continue;
        for (int k = 0; k < pd; ++k)
            if (who[k][tl] < 0) { who[k][tl] = nrk[j][tl]; break; }
    }
    // emit only pd slots (sim gates reads by ngrp, tail groups never dereferenced)
    for (int k = 0; k < pd; ++k) {
        int v = who[k][tl];
        int word;
        if (v < 0) {
            word = 3072 + ((l + k) & 31);
        } else {
            int bank = (l + k) & 31;
            BANKS(v, b0, b1, b2)
            word = (b0 == bank) ? v
                 : (b1 == bank) ? bofsB(v)
                 : (b2 == bank) ? bofsC(v)
                 : v;
        }
        nbr8[((k >> 3) << 13) + (r << 3) + (k & 7)] = (u16)(word * 4);
    }
#undef BANKS
    ngrp_r[r] = pd >> 3;
    invd_r[r] = 0.35f / ((float)dg + 1e-7f);   // OMEGA*GAMMA/(in_deg+1e-7)
}

// LDS-only barrier: order LDS ops, do NOT drain vmcnt.
#define LDS_BARRIER() asm volatile("s_waitcnt lgkmcnt(0)\n\ts_barrier" ::: "memory")

// ---------------- main simulation ----------------
__global__ __launch_bounds__(1024, 1) void sim_kernel(
    const float* __restrict__ x0, const float* __restrict__ t,
    const float* __restrict__ speed, const float* __restrict__ vola,
    const float* __restrict__ noise, const int* __restrict__ items,
    const u16* __restrict__ nbr8, const int* __restrict__ node_of,
    const int* __restrict__ rank_of,
    const int* __restrict__ ngrp_r, const float* __restrict__ invd_r,
    float* __restrict__ out)
{
    __shared__ float xb0[3104];         // step-even source buffer (A+B+C+sentinels)
    __shared__ float xb1[3104];         // step-odd  source buffer
    __shared__ float4 cst[TT - 1];      // per-step {e, scale, item_as_float, -}

    const int s   = blockIdx.x;
    const int tid = threadIdx.x;

    const float sp = speed[s];
    const float vo = vola[s];

    if (tid < TT - 1) {
        float t0 = t[s * TT + tid], t1 = t[s * TT + tid + 1];
        float dt = t1 - t0;
        float e  = expf(-sp * dt);
        float sc = vo * sqrtf((1.0f - e * e) / (2.0f * sp + 1e-6f));
        int   it = items[s * TT + tid + 1];
        cst[tid] = make_float4(e, sc, __int_as_float(it), 0.0f);
    }

    const int   m     = node_of[tid];     // node this thread simulates
    const int   r_out = rank_of[tid];     // rank holding node `tid` (for out staging)
    const int   wB    = bofsB(tid);
    const int   wC    = bofsC(tid);

    const float x0m = x0[m];
    xb0[tid] = x0m;
    xb0[wB]  = x0m;
    xb0[wC]  = x0m;
    if (tid < 32) { xb0[3072 + tid] = 0.0f; xb1[3072 + tid] = 0.0f; }

    float* __restrict__ outp = out + (size_t)s * TT * NN + tid;
    outp[0] = x0[tid];                    // coalesced

    const int   ng   = ngrp_r[tid];
    const float invd = invd_r[tid];
    const int   item0 = items[s * TT];
    float a_f = (m == item0) ? 1.0f : 0.0f;
    float s_f = 0.0f;

    // per-node noise register pipeline, 2 steps ahead
    const float* __restrict__ nzm = noise + (size_t)s * (TT - 1) * NN + m;
    float nzA = nzm[0];
    float nzB = nzm[NN];

    // neighbor byte-offset groups: 0-3 pre-extracted to scalar regs, 4-11 packed
    const uint4* __restrict__ nb = (const uint4*)nbr8 + tid;   // group stride 1024
    uint4 q0  = nb[0];
    uint4 q1  = nb[1024];
    uint4 q2  = nb[2048];
    uint4 q3  = nb[3072];
    uint4 q4  = nb[4096];
    uint4 q5  = nb[5120];
    uint4 q6  = nb[6144];
    uint4 q7  = nb[7168];
    uint4 q8  = nb[8192];
    uint4 q9  = nb[9216];
    uint4 q10 = nb[10240];
    uint4 q11 = nb[11264];

    int a00=q0.x&0xFFFF, a01=q0.x>>16, a02=q0.y&0xFFFF, a03=q0.y>>16,
        a04=q0.z&0xFFFF, a05=q0.z>>16, a06=q0.w&0xFFFF, a07=q0.w>>16;
    int a10=q1.x&0xFFFF, a11=q1.x>>16, a12=q1.y&0xFFFF, a13=q1.y>>16,
        a14=q1.z&0xFFFF, a15=q1.z>>16, a16=q1.w&0xFFFF, a17=q1.w>>16;
    int a20=q2.x&0xFFFF, a21=q2.x>>16, a22=q2.y&0xFFFF, a23=q2.y>>16,
        a24=q2.z&0xFFFF, a25=q2.z>>16, a26=q2.w&0xFFFF, a27=q2.w>>16;
    int a30=q3.x&0xFFFF, a31=q3.x>>16, a32=q3.y&0xFFFF, a33=q3.y>>16,
        a34=q3.z&0xFFFF, a35=q3.z>>16, a36=q3.w&0xFFFF, a37=q3.w>>16;

    __syncthreads();                      // one full barrier after init

    float x_own = x0m;

#define LD(BASE, OFF) (*(const float*)((const char*)(BASE) + (OFF)))
#define G8A(BASE, A)                                                   \
    acc += LD(BASE, A##0); acc += LD(BASE, A##1);                      \
    acc += LD(BASE, A##2); acc += LD(BASE, A##3);                      \
    acc += LD(BASE, A##4); acc += LD(BASE, A##5);                      \
    acc += LD(BASE, A##6); acc += LD(BASE, A##7);
#define G8P(BASE, V)                                                   \
    acc += LD(BASE, (V).x & 0xFFFFu); acc += LD(BASE, (V).x >> 16);    \
    acc += LD(BASE, (V).y & 0xFFFFu); acc += LD(BASE, (V).y >> 16);    \
    acc += LD(BASE, (V).z & 0xFFFFu); acc += LD(BASE, (V).z >> 16);    \
    acc += LD(BASE, (V).w & 0xFFFFu); acc += LD(BASE, (V).w >> 16);

#define STEP(SRC, DST, I)                                              \
    {                                                                  \
        const int i_ = (I);                                            \
        const float4 c = cst[i_];                                      \
        int ipre = (i_ + 2 < TT - 1) ? (i_ + 2) : (TT - 2);            \
        float nz_new = nzm[(size_t)ipre * NN];                         \
        float xi_lin = SRC[r_out];                                     \
        float acc = 0.0f;                                              \
        G8A(SRC, a0) G8A(SRC, a1)                                      \
        if (ng > 2) { G8A(SRC, a2)                                     \
        if (ng > 3) { G8A(SRC, a3)                                     \
        if (ng > 4) { G8P(SRC, q4)                                     \
        if (ng > 5) { G8P(SRC, q5)                                     \
        if (ng > 6) { G8P(SRC, q6)                                     \
        if (ng > 7) { G8P(SRC, q7)                                     \
        if (ng > 8) { G8P(SRC, q8)                                     \
        if (ng > 9) { G8P(SRC, q9)                                     \
        if (ng > 10){ G8P(SRC, q10)                                    \
        if (ng > 11){ G8P(SRC, q11) } } } } } } } } } }                \
        float nz = nzA * c.y;                                          \
        float r  = s_f / (a_f + 1e-6f);                                \
        float level = fmaf(acc, invd, 0.5f * r * r);                   \
        float xn = fmaf(x_own, c.x, fmaf(1.0f - c.x, level, nz));      \
        DST[tid] = xn;                                                 \
        DST[wB]  = xn;                                                 \
        DST[wC]  = xn;                                                 \
        if (i_) outp[(size_t)i_ * NN] = xi_lin;                        \
        if (m == __float_as_int(c.z)) {                                \
            a_f += 1.0f;                                               \
            s_f += (xn >= 0.0f) ? 1.0f : 0.0f;                         \
        }                                                              \
        x_own = xn;                                                    \
        nzA = nzB; nzB = nz_new;                                       \
        LDS_BARRIER();                                                 \
    }

    for (int i = 0; i < TT - 2; i += 2) {
        STEP(xb0, xb1, i);
        STEP(xb1, xb0, i + 1);
    }
    STEP(xb0, xb1, TT - 2);               // step index 254 (even), xb0 -> xb1

#undef STEP
#undef G8P
#undef G8A
#undef LD

    outp[(size_t)(TT - 1) * NN] = xb1[r_out];   // final state is in xb1
}

extern "C" void kernel_launch(void* const* d_in, const int* in_sizes, int n_in,
                              void* d_out, int out_size, void* d_ws, size_t ws_size,
                              hipStream_t stream)
{
    const float* x0    = (const float*)d_in[0];
    const float* t     = (const float*)d_in[1];
    const float* speed = (const float*)d_in[2];
    const float* vola  = (const float*)d_in[3];
    const float* adj   = (const float*)d_in[4];
    const float* noise = (const float*)d_in[5];
    const int*   items = (const int*)d_in[6];
    float* out = (float*)d_out;

    char* ws = (char*)d_ws;
    int*   cnt_part = (int*)ws;                       // 64 KB
    int*   deg      = (int*)(ws + 65536);             // 4 KB
    int*   pdeg     = (int*)(ws + 65536 + 4096);      // 4 KB
    int*   rank_of  = (int*)(ws + 65536 + 8192);      // 4 KB
    int*   node_of  = (int*)(ws + 65536 + 12288);     // 4 KB
    int*   ngrp_r   = (int*)(ws + 65536 + 16384);     // 4 KB
    float* invd_r   = (float*)(ws + 65536 + 20480);   // 4 KB
    u16*   nbrC     = (u16*)(ws + 65536 + 24576);     // 192 KB
    u16*   nbr8     = (u16*)(ws + 65536 + 24576 + 196608); // 192 KB

    k1_count<<<256, 64, 0, stream>>>(adj, cnt_part);
    k2_totals<<<4, 256, 0, stream>>>(cnt_part, deg, pdeg);
    k3_rank<<<4, 256, 0, stream>>>(pdeg, rank_of, node_of);
    k4_fill<<<256, 64, 0, stream>>>(adj, cnt_part, nbrC);
    k5_sched<<<16, 64, 0, stream>>>(nbrC, deg, pdeg, rank_of, nbr8, ngrp_r, invd_r);
    sim_kernel<<<64, 1024, 0, stream>>>(x0, t, speed, vola, noise, items,
                                        nbr8, node_of, rank_of, ngrp_r, invd_r, out);
}

// Round 9
// 454.051 us; speedup vs baseline: 1.5619x; 1.5619x over previous
//
#include <hip/hip_runtime.h>

#define NN 1024
#define TT 256
#define MAXDEG 96

typedef unsigned short u16;

// LDS x layout (words, rank-indexed), per buffer xb[b][3104]:
//   [0..1023]    copy A: rank v at word v                      (bank v&31)
//   [1024..2047] copy B: word 1024 + ((v&~31)|((v&31)^h)),     h=(v>>5)&31   (bank (v&31)^h)
//   [2048..3071] copy C: word 2048 + ((v&~31)|((v&31)^((13h+5)&31)))
//   [3072..3103] zero sentinels (one per bank)

__device__ __forceinline__ int bofsB(int v) {
    int h = (v >> 5) & 31;
    return 1024 + ((v & ~31) | ((v & 31) ^ h));
}
__device__ __forceinline__ int bofsC(int v) {
    int h = (v >> 5) & 31;
    return 2048 + ((v & ~31) | ((v & 31) ^ ((13 * h + 5) & 31)));
}

// ---- K1: per-chunk nonzero counts of each adj column (coalesced) ----
__global__ __launch_bounds__(64) void k1_count(const float* __restrict__ adj,
                                               int* __restrict__ cnt_part)
{
    int tid = blockIdx.x * 64 + threadIdx.x;
    int chunk = tid >> 10;
    int n = tid & 1023;
    int c = 0;
    for (int j = 0; j < 64; ++j)
        c += (adj[(chunk * 64 + j) * NN + n] != 0.0f) ? 1 : 0;
    cnt_part[chunk * NN + n] = c;
}

// ---- K2: totals -> deg, pdeg (slack +8..15 for the bank matcher) ----
__global__ __launch_bounds__(256) void k2_totals(const int* __restrict__ cnt_part,
                                                 int* __restrict__ deg,
                                                 int* __restrict__ pdeg)
{
    int n = blockIdx.x * 256 + threadIdx.x;
    int tot = 0;
    for (int c = 0; c < 16; ++c) tot += cnt_part[c * NN + n];
    deg[n] = tot;
    int cap = tot < MAXDEG ? tot : MAXDEG;
    int pd = (cap + 15) & ~7;
    if (pd < 16) pd = 16;
    if (pd > MAXDEG) pd = MAXDEG;
    pdeg[n] = pd;
}

// ---- K3: stable descending-pdeg rank ----
__global__ __launch_bounds__(256) void k3_rank(const int* __restrict__ pdeg,
                                               int* __restrict__ rank_of,
                                               int* __restrict__ node_of)
{
    int n = blockIdx.x * 256 + threadIdx.x;
    int my = pdeg[n];
    int r = 0;
    for (int m = 0; m < NN; ++m) {
        int pm = pdeg[m];
        r += (pm > my) || (pm == my && m < n);
    }
    rank_of[n] = r;
    node_of[r] = n;
}

// ---- K4: fill compact neighbor lists (coalesced column scan) ----
__global__ __launch_bounds__(64) void k4_fill(const float* __restrict__ adj,
                                              const int* __restrict__ cnt_part,
                                              u16* __restrict__ nbrC)
{
    int tid = blockIdx.x * 64 + threadIdx.x;
    int chunk = tid >> 10;
    int n = tid & 1023;
    int pos = 0;
    for (int c = 0; c < chunk; ++c) pos += cnt_part[c * NN + n];
    for (int j = 0; j < 64; ++j) {
        int m = chunk * 64 + j;
        if (adj[m * NN + n] != 0.0f) {
            if (pos < MAXDEG) nbrC[n * MAXDEG + pos] = (u16)m;
            ++pos;
        }
    }
}

// ---- K5: count-based three-choice greedy bank schedule (O(1)/neighbor) ----
// slot k of lane l targets bank (l+k)&31. Per residue class res (k mod 32) keep
// only a FREE COUNT; slot index derived arithmetically. No probing chains.
__device__ __forceinline__ int cnt_res(int pd, int res) {
    return (pd > res) ? (((pd - 1 - res) >> 5) + 1) : 0;
}

__global__ __launch_bounds__(64) void k5_sched(const u16* __restrict__ nbrC,
                                               const int* __restrict__ deg,
                                               const int* __restrict__ pdeg,
                                               const int* __restrict__ rank_of,
                                               u16* __restrict__ nbr8,
                                               int* __restrict__ ngrp_r,
                                               float* __restrict__ invd_r)
{
    __shared__ int freec[32][64];    // free slots per residue, lane-major (bank=tl&31)
    const int tl = threadIdx.x;
    const int n  = blockIdx.x * 64 + tl;
    const int r  = rank_of[n];
    const int l  = r & 63;
    const int dg = deg[n];
    const int cap = dg < MAXDEG ? dg : MAXDEG;
    const int pd = pdeg[n];

    for (int res = 0; res < 32; ++res)
        freec[res][tl] = cnt_res(pd, res);

    // sentinel-prefill all pd slots (assignments overwrite)
    for (int k = 0; k < pd; ++k) {
        int word = 3072 + ((l + k) & 31);
        nbr8[((k >> 3) << 13) + (r << 3) + (k & 7)] = (u16)(word * 4);
    }

    for (int j = 0; j < cap; ++j) {
        int v = rank_of[nbrC[n * MAXDEG + j]];
        int b0 = v & 31;
        int h  = (v >> 5) & 31;
        int b1 = b0 ^ h;
        int b2 = b0 ^ ((13 * h + 5) & 31);
        int res0 = (b0 - l) & 31;
        int res1 = (b1 - l) & 31;
        int res2 = (b2 - l) & 31;
        int kslot, word;
        int f0 = freec[res0][tl];
        if (f0 > 0) {
            kslot = res0 + 32 * (cnt_res(pd, res0) - f0);
            freec[res0][tl] = f0 - 1;
            word = v;
        } else {
            int f1 = freec[res1][tl];
            if (f1 > 0) {
                kslot = res1 + 32 * (cnt_res(pd, res1) - f1);
                freec[res1][tl] = f1 - 1;
                word = bofsB(v);
            } else {
                int f2 = freec[res2][tl];
                if (f2 > 0) {
                    kslot = res2 + 32 * (cnt_res(pd, res2) - f2);
                    freec[res2][tl] = f2 - 1;
                    word = bofsC(v);
                } else {
                    kslot = -1; word = v;          // overflow: any free residue
                    for (int res = 0; res < 32; ++res) {
                        int f = freec[res][tl];
                        if (f > 0) {
                            kslot = res + 32 * (cnt_res(pd, res) - f);
                            freec[res][tl] = f - 1;
                            break;
                        }
                    }
                }
            }
        }
        if (kslot >= 0)
            nbr8[((kslot >> 3) << 13) + (r << 3) + (kslot & 7)] = (u16)(word * 4);
    }
    ngrp_r[r] = pd >> 3;
    invd_r[r] = 0.35f / ((float)dg + 1e-7f);   // OMEGA*GAMMA/(in_deg+1e-7)
}

// LDS-only barrier: order LDS ops, do NOT drain vmcnt.
#define LDS_BARRIER() asm volatile("s_waitcnt lgkmcnt(0)\n\ts_barrier" ::: "memory")

// ---------------- main simulation (R7 structure, verbatim) ----------------
__global__ __launch_bounds__(1024) void sim_kernel(
    const float* __restrict__ x0, const float* __restrict__ t,
    const float* __restrict__ speed, const float* __restrict__ vola,
    const float* __restrict__ noise, const int* __restrict__ items,
    const u16* __restrict__ nbr8, const int* __restrict__ node_of,
    const int* __restrict__ rank_of,
    const int* __restrict__ ngrp_r, const float* __restrict__ invd_r,
    float* __restrict__ out)
{
    __shared__ float xb[2][3104];       // A + B + C copies + 32 zero sentinels
    __shared__ float4 cst[TT - 1];      // per-step {e, scale, item_as_float, -}

    const int s   = blockIdx.x;
    const int tid = threadIdx.x;

    const float sp = speed[s];
    const float vo = vola[s];

    if (tid < TT - 1) {
        float t0 = t[s * TT + tid], t1 = t[s * TT + tid + 1];
        float dt = t1 - t0;
        float e  = expf(-sp * dt);
        float sc = vo * sqrtf((1.0f - e * e) / (2.0f * sp + 1e-6f));
        int   it = items[s * TT + tid + 1];
        cst[tid] = make_float4(e, sc, __int_as_float(it), 0.0f);
    }

    const int   m     = node_of[tid];     // node this thread simulates
    const int   r_out = rank_of[tid];     // rank holding node `tid` (for out staging)
    const int   wB    = bofsB(tid);       // this thread's copy-B/C write words
    const int   wC    = bofsC(tid);

    const float x0m = x0[m];
    xb[0][tid] = x0m;
    xb[0][wB]  = x0m;
    xb[0][wC]  = x0m;
    if (tid < 32) { xb[0][3072 + tid] = 0.0f; xb[1][3072 + tid] = 0.0f; }

    float* __restrict__ outp = out + (size_t)s * TT * NN + tid;
    outp[0] = x0[tid];                    // coalesced

    const int   ng   = ngrp_r[tid];
    const float invd = invd_r[tid];
    const int   item0 = items[s * TT];
    float a_f = (m == item0) ? 1.0f : 0.0f;
    float s_f = 0.0f;

    // per-node noise register pipeline, 2 steps ahead
    const float* __restrict__ nzm = noise + (size_t)s * (TT - 1) * NN + m;
    float nzA = nzm[0];
    float nzB = nzm[NN];

    // preload ALL neighbor index groups into registers
    const uint4* __restrict__ nb = (const uint4*)nbr8 + tid;   // group stride 1024
    uint4 q0  = nb[0];
    uint4 q1  = nb[1024];
    uint4 q2  = nb[2048];
    uint4 q3  = nb[3072];
    uint4 q4  = nb[4096];
    uint4 q5  = nb[5120];
    uint4 q6  = nb[6144];
    uint4 q7  = nb[7168];
    uint4 q8  = nb[8192];
    uint4 q9  = nb[9216];
    uint4 q10 = nb[10240];
    uint4 q11 = nb[11264];

    __syncthreads();                      // one full barrier after init

    float x_own = x0m;

#define G8(V)                                                   \
    acc += *(const float*)(xc + ((V).x & 0xFFFFu));             \
    acc += *(const float*)(xc + ((V).x >> 16));                 \
    acc += *(const float*)(xc + ((V).y & 0xFFFFu));             \
    acc += *(const float*)(xc + ((V).y >> 16));                 \
    acc += *(const float*)(xc + ((V).z & 0xFFFFu));             \
    acc += *(const float*)(xc + ((V).z >> 16));                 \
    acc += *(const float*)(xc + ((V).w & 0xFFFFu));             \
    acc += *(const float*)(xc + ((V).w >> 16));

    for (int i = 0; i < TT - 1; ++i) {
        const float* __restrict__ src = xb[i & 1];
        float* __restrict__ dst       = xb[(i + 1) & 1];
        const float4 c = cst[i];

        // prefetch noise for step i+2 (latency hidden across 2 barriers)
        int ipre = (i + 2 < TT - 1) ? (i + 2) : (TT - 2);
        float nz_new = nzm[(size_t)ipre * NN];

        float xi_lin = src[r_out];        // prev value of node `tid` (permutation read)

        float acc = 0.0f;
        const char* xc = (const char*)src;
        G8(q0); G8(q1);
        if (ng > 2) { G8(q2);
        if (ng > 3) { G8(q3);
        if (ng > 4) { G8(q4);
        if (ng > 5) { G8(q5);
        if (ng > 6) { G8(q6);
        if (ng > 7) { G8(q7);
        if (ng > 8) { G8(q8);
        if (ng > 9) { G8(q9);
        if (ng > 10){ G8(q10);
        if (ng > 11){ G8(q11); } } } } } } } } } }

        float nz = nzA * c.y;
        float r  = s_f / (a_f + 1e-6f);
        float level = fmaf(acc, invd, 0.5f * r * r);
        float xn = fmaf(x_own, c.x, fmaf(1.0f - c.x, level, nz));

        dst[tid] = xn;                    // copy A: linear, conflict-free
        dst[wB]  = xn;                    // copy B: XOR-permuted, conflict-free
        dst[wC]  = xn;                    // copy C: XOR-permuted, conflict-free
        if (i) outp[(size_t)i * NN] = xi_lin;          // coalesced, 1-step delayed

        if (m == __float_as_int(c.z)) {
            a_f += 1.0f;
            s_f += (xn >= 0.0f) ? 1.0f : 0.0f;
        }
        x_own = xn;
        nzA = nzB; nzB = nz_new;
        LDS_BARRIER();                    // LDS-only: no vmcnt drain
    }
#undef G8

    outp[(size_t)(TT - 1) * NN] = xb[1][r_out];   // final state lives in buffer 1
}

extern "C" void kernel_launch(void* const* d_in, const int* in_sizes, int n_in,
                              void* d_out, int out_size, void* d_ws, size_t ws_size,
                              hipStream_t stream)
{
    const float* x0    = (const float*)d_in[0];
    const float* t     = (const float*)d_in[1];
    const float* speed = (const float*)d_in[2];
    const float* vola  = (const float*)d_in[3];
    const float* adj   = (const float*)d_in[4];
    const float* noise = (const float*)d_in[5];
    const int*   items = (const int*)d_in[6];
    float* out = (float*)d_out;

    char* ws = (char*)d_ws;
    int*   cnt_part = (int*)ws;                       // 64 KB
    int*   deg      = (int*)(ws + 65536);             // 4 KB
    int*   pdeg     = (int*)(ws + 65536 + 4096);      // 4 KB
    int*   rank_of  = (int*)(ws + 65536 + 8192);      // 4 KB
    int*   node_of  = (int*)(ws + 65536 + 12288);     // 4 KB
    int*   ngrp_r   = (int*)(ws + 65536 + 16384);     // 4 KB
    float* invd_r   = (float*)(ws + 65536 + 20480);   // 4 KB
    u16*   nbrC     = (u16*)(ws + 65536 + 24576);     // 192 KB
    u16*   nbr8     = (u16*)(ws + 65536 + 24576 + 196608); // 192 KB

    k1_count<<<256, 64, 0, stream>>>(adj, cnt_part);
    k2_totals<<<4, 256, 0, stream>>>(cnt_part, deg, pdeg);
    k3_rank<<<4, 256, 0, stream>>>(pdeg, rank_of, node_of);
    k4_fill<<<256, 64, 0, stream>>>(adj, cnt_part, nbrC);
    k5_sched<<<16, 64, 0, stream>>>(nbrC, deg, pdeg, rank_of, nbr8, ngrp_r, invd_r);
    sim_kernel<<<64, 1024, 0, stream>>>(x0, t, speed, vola, noise, items,
                                        nbr8, node_of, rank_of, ngrp_r, invd_r, out);
}